// Round 3
// baseline (1168.959 us; speedup 1.0000x reference)
//
#include <hip/hip_runtime.h>

#define NB 4096
#define NT 1024

typedef float f2 __attribute__((ext_vector_type(2)));
typedef float f4 __attribute__((ext_vector_type(4)));

// Quad gate layout: lane = 4*q + g, g in {0:i, 1:f, 2:g~, 3:o}, q = hidden unit.
// After per-lane activation, broadcast the 4 gate values within each quad via DPP.
#define GATE(accv, creg, hout) {                                              \
    float e_ = __builtin_amdgcn_exp2f((accv) * kpre);                         \
    float r_ = __builtin_amdgcn_rcpf(1.0f + e_);                              \
    float a_ = fmaf(r_, kA, kB);                                              \
    int ai_ = __float_as_int(a_);                                             \
    float iv_ = __int_as_float(__builtin_amdgcn_mov_dpp(ai_, 0x00, 0xF, 0xF, 0)); \
    float fv_ = __int_as_float(__builtin_amdgcn_mov_dpp(ai_, 0x55, 0xF, 0xF, 0)); \
    float gv_ = __int_as_float(__builtin_amdgcn_mov_dpp(ai_, 0xAA, 0xF, 0xF, 0)); \
    float ov_ = __int_as_float(__builtin_amdgcn_mov_dpp(ai_, 0xFF, 0xF, 0xF, 0)); \
    creg = fmaf(fv_, creg, iv_ * gv_);                                        \
    float e2_ = __builtin_amdgcn_exp2f(creg * -2.88539008177792681f);         \
    float r2_ = __builtin_amdgcn_rcpf(1.0f + e2_);                            \
    hout = ov_ * fmaf(r2_, 2.0f, -1.0f);                                      \
}

__global__ __launch_bounds__(256, 4) void lstm3_kernel(
    const float* __restrict__ x,
    const float* __restrict__ h0,
    const float* __restrict__ c0,
    const float* __restrict__ Wih0, const float* __restrict__ Whh0,
    const float* __restrict__ bih0, const float* __restrict__ bhh0,
    const float* __restrict__ Wih1, const float* __restrict__ Whh1,
    const float* __restrict__ bih1, const float* __restrict__ bhh1,
    const float* __restrict__ Wih2, const float* __restrict__ Whh2,
    const float* __restrict__ bih2, const float* __restrict__ bhh2,
    const float* __restrict__ Wfc,  const float* __restrict__ bfc,
    float* __restrict__ out)
{
    __shared__ float ldsH[3][4][16];   // h vectors, slot j = h[j], per wave
    __shared__ float ldsX[4][64];      // x staging: 32 steps * 2 floats per wave

    const int lane = threadIdx.x & 63;
    const int wv   = threadIdx.x >> 6;
    const int b    = (blockIdx.x << 2) + wv;
    const int q    = lane >> 2;        // hidden unit 0..15
    const int g    = lane & 3;         // gate 0:i 1:f 2:g 3:o
    const int row  = g * 16 + q;       // PyTorch gate-row index

    const float kpre = (g == 2) ? -2.88539008177792681f : -1.44269504088896340f;
    const float kA   = (g == 2) ? 2.0f : 1.0f;
    const float kB   = (g == 2) ? -1.0f : 0.0f;

    // ---- per-lane weight rows as f4 (16B-aligned global loads), pinned in VGPRs ----
    f2 wi0 = *(const f2*)&Wih0[row * 2];
    f4 wh0[4], wi1[4], wh1[4], wi2[4], wh2[4];
#pragma unroll
    for (int k = 0; k < 4; ++k) {
        wh0[k] = *(const f4*)&Whh0[row * 16 + 4 * k];
        wi1[k] = *(const f4*)&Wih1[row * 16 + 4 * k];
        wh1[k] = *(const f4*)&Whh1[row * 16 + 4 * k];
        wi2[k] = *(const f4*)&Wih2[row * 16 + 4 * k];
        wh2[k] = *(const f4*)&Whh2[row * 16 + 4 * k];
    }
    float bias0 = bih0[row] + bhh0[row];
    float bias1 = bih1[row] + bhh1[row];
    float bias2 = bih2[row] + bhh2[row];
    // Pin: forbid rematerialization / AGPR parking of loop-invariant weights.
    asm volatile("" : "+v"(wh0[0]), "+v"(wh0[1]), "+v"(wh0[2]), "+v"(wh0[3]));
    asm volatile("" : "+v"(wi1[0]), "+v"(wi1[1]), "+v"(wi1[2]), "+v"(wi1[3]));
    asm volatile("" : "+v"(wh1[0]), "+v"(wh1[1]), "+v"(wh1[2]), "+v"(wh1[3]));
    asm volatile("" : "+v"(wi2[0]), "+v"(wi2[1]), "+v"(wi2[2]), "+v"(wi2[3]));
    asm volatile("" : "+v"(wh2[0]), "+v"(wh2[1]), "+v"(wh2[2]), "+v"(wh2[3]));
    asm volatile("" : "+v"(wi0), "+v"(bias0), "+v"(bias1), "+v"(bias2));

    // ---- initial state ----
    float c0r = c0[0 * NB * 16 + b * 16 + q];
    float c1r = c0[1 * NB * 16 + b * 16 + q];
    float c2r = c0[2 * NB * 16 + b * 16 + q];
    if (lane < 16) {
        ldsH[0][wv][lane] = h0[0 * NB * 16 + b * 16 + lane];
        ldsH[1][wv][lane] = h0[1 * NB * 16 + b * 16 + lane];
        ldsH[2][wv][lane] = h0[2 * NB * 16 + b * 16 + lane];
    }
    __builtin_amdgcn_wave_barrier();

    const f4* __restrict__ hb0 = (const f4*)&ldsH[0][wv][0];
    const f4* __restrict__ hb1 = (const f4*)&ldsH[1][wv][0];
    const f4* __restrict__ hb2 = (const f4*)&ldsH[2][wv][0];
    const f2* __restrict__ xb  = (const f2*)&ldsX[wv][0];

    // prefetch x chunk 0 (64 floats = 32 timesteps * 2 comps)
    float xpre = x[(size_t)b * (NT * 2) + lane];

    for (int ch = 0; ch < (NT * 2) / 64; ++ch) {
        ldsX[wv][lane] = xpre;
        __builtin_amdgcn_wave_barrier();
        if (ch + 1 < (NT * 2) / 64)
            xpre = x[(size_t)b * (NT * 2) + (ch + 1) * 64 + lane];

#pragma unroll 2
        for (int s = 0; s < 32; ++s) {
            const f2 x2 = xb[s];

            // ================= layer 0 =================
            f4 ha = hb0[0], hc = hb0[1], hd = hb0[2], he = hb0[3];
            f4 a0 = wh0[0] * ha;
            f4 a1 = wh0[1] * hc;
            a0 = wh0[2] * hd + a0;
            a1 = wh0[3] * he + a1;
            a0 = a0 + a1;
            f2 s2 = __builtin_shufflevector(a0, a0, 0, 1)
                  + __builtin_shufflevector(a0, a0, 2, 3);
            float acc = (s2.x + s2.y) + fmaf(wi0.x, x2.x, fmaf(wi0.y, x2.y, bias0));
            float hn0;
            GATE(acc, c0r, hn0);
            if (g == 0) ldsH[0][wv][q] = hn0;
            __builtin_amdgcn_wave_barrier();

            // ================= layer 1 =================
            ha = hb1[0]; hc = hb1[1]; hd = hb1[2]; he = hb1[3];
            f4 xa = hb0[0], xc = hb0[1], xd = hb0[2], xe = hb0[3];  // fresh h0
            a0 = wh1[0] * ha;
            a1 = wh1[1] * hc;
            f4 a2 = wh1[2] * hd;
            f4 a3 = wh1[3] * he;
            a0 = wi1[0] * xa + a0;
            a1 = wi1[1] * xc + a1;
            a2 = wi1[2] * xd + a2;
            a3 = wi1[3] * xe + a3;
            a0 = a0 + a1;
            a2 = a2 + a3;
            a0 = a0 + a2;
            s2 = __builtin_shufflevector(a0, a0, 0, 1)
               + __builtin_shufflevector(a0, a0, 2, 3);
            acc = (s2.x + s2.y) + bias1;
            float hn1;
            GATE(acc, c1r, hn1);
            if (g == 0) ldsH[1][wv][q] = hn1;
            __builtin_amdgcn_wave_barrier();

            // ================= layer 2 =================
            ha = hb2[0]; hc = hb2[1]; hd = hb2[2]; he = hb2[3];
            xa = hb1[0]; xc = hb1[1]; xd = hb1[2]; xe = hb1[3];    // fresh h1
            a0 = wh2[0] * ha;
            a1 = wh2[1] * hc;
            a2 = wh2[2] * hd;
            a3 = wh2[3] * he;
            a0 = wi2[0] * xa + a0;
            a1 = wi2[1] * xc + a1;
            a2 = wi2[2] * xd + a2;
            a3 = wi2[3] * xe + a3;
            a0 = a0 + a1;
            a2 = a2 + a3;
            a0 = a0 + a2;
            s2 = __builtin_shufflevector(a0, a0, 0, 1)
               + __builtin_shufflevector(a0, a0, 2, 3);
            acc = (s2.x + s2.y) + bias2;
            float hn2;
            GATE(acc, c2r, hn2);
            if (g == 0) ldsH[2][wv][q] = hn2;
            __builtin_amdgcn_wave_barrier();
        }
    }

    // ---- epilogue: out[b] = Wfc . h2[T-1] + bfc ----
    if (lane == 0) {
        float s = bfc[0];
#pragma unroll
        for (int k = 0; k < 16; ++k) s = fmaf(ldsH[2][wv][k], Wfc[k], s);
        out[b] = s;
    }
}

extern "C" void kernel_launch(void* const* d_in, const int* in_sizes, int n_in,
                              void* d_out, int out_size, void* d_ws, size_t ws_size,
                              hipStream_t stream) {
    (void)in_sizes; (void)n_in; (void)d_ws; (void)ws_size; (void)out_size;
    const float* x    = (const float*)d_in[0];
    const float* h0   = (const float*)d_in[1];
    const float* c0   = (const float*)d_in[2];
    const float* Wih0 = (const float*)d_in[3];
    const float* Whh0 = (const float*)d_in[4];
    const float* bih0 = (const float*)d_in[5];
    const float* bhh0 = (const float*)d_in[6];
    const float* Wih1 = (const float*)d_in[7];
    const float* Whh1 = (const float*)d_in[8];
    const float* bih1 = (const float*)d_in[9];
    const float* bhh1 = (const float*)d_in[10];
    const float* Wih2 = (const float*)d_in[11];
    const float* Whh2 = (const float*)d_in[12];
    const float* bih2 = (const float*)d_in[13];
    const float* bhh2 = (const float*)d_in[14];
    const float* Wfc  = (const float*)d_in[15];
    const float* bfc  = (const float*)d_in[16];
    float* out = (float*)d_out;

    lstm3_kernel<<<NB / 4, 256, 0, stream>>>(
        x, h0, c0, Wih0, Whh0, bih0, bhh0, Wih1, Whh1, bih1, bhh1,
        Wih2, Whh2, bih2, bhh2, Wfc, bfc, out);
}

// Round 4
// 1060.192 us; speedup vs baseline: 1.1026x; 1.1026x over previous
//
#include <hip/hip_runtime.h>

#define NB 4096
#define NT 1024

typedef float f2 __attribute__((ext_vector_type(2)));
typedef float f4 __attribute__((ext_vector_type(4)));

// Quad layout within a wave: lane = 4*q + g; q = hidden unit 0..15, g = gate
// (0:i 1:f 2:g~ 3:o). All 4 lanes of a quad end up with all 4 gate values via
// DPP quad broadcasts, so every lane computes c,h for its unit redundantly.
#define GATE(accv, creg, hout) {                                              \
    float e_ = __builtin_amdgcn_exp2f((accv) * kpre);                         \
    float r_ = __builtin_amdgcn_rcpf(1.0f + e_);                              \
    float a_ = fmaf(r_, kA, kB);                                              \
    int ai_ = __float_as_int(a_);                                             \
    float iv_ = __int_as_float(__builtin_amdgcn_mov_dpp(ai_, 0x00, 0xF, 0xF, 0)); \
    float fv_ = __int_as_float(__builtin_amdgcn_mov_dpp(ai_, 0x55, 0xF, 0xF, 0)); \
    float gv_ = __int_as_float(__builtin_amdgcn_mov_dpp(ai_, 0xAA, 0xF, 0xF, 0)); \
    float ov_ = __int_as_float(__builtin_amdgcn_mov_dpp(ai_, 0xFF, 0xF, 0xF, 0)); \
    creg = fmaf(fv_, creg, iv_ * gv_);                                        \
    float e2_ = __builtin_amdgcn_exp2f(creg * -2.88539008177792681f);         \
    float r2_ = __builtin_amdgcn_rcpf(1.0f + e2_);                            \
    hout = ov_ * fmaf(r2_, 2.0f, -1.0f);                                      \
}

#define F2LO(v) __builtin_shufflevector(v, v, 0, 1)
#define F2HI(v) __builtin_shufflevector(v, v, 2, 3)

// Load the 16-float h vector at LDS address hb (uniform broadcast) into 8 f2s.
#define LOAD_H16(dst, hb) {                                                   \
    f4 v0_ = *(const f4*)((hb) + 0);                                          \
    f4 v1_ = *(const f4*)((hb) + 4);                                          \
    f4 v2_ = *(const f4*)((hb) + 8);                                          \
    f4 v3_ = *(const f4*)((hb) + 12);                                         \
    dst[0] = F2LO(v0_); dst[1] = F2HI(v0_);                                   \
    dst[2] = F2LO(v1_); dst[3] = F2HI(v1_);                                   \
    dst[4] = F2LO(v2_); dst[5] = F2HI(v2_);                                   \
    dst[6] = F2LO(v3_); dst[7] = F2HI(v3_);                                   \
}

// One pipeline super-step with static buffer parities P (write side for w0/w2)
// and Q = P^1. Derivation (s = super-step, P = s&1):
//   wave0 (t=s):    reads own H0[Q],            writes H0[P]
//   wave1 (t=s-1):  reads in H0[Q], own H1[P],  writes H1[Q]
//   wave2 (t=s-2):  reads in H1[P], own H2[Q],  writes H2[P]
#define STEP(S, P, Q)                                                         \
{                                                                             \
    if (w == 0) {                                                             \
        if ((S) < NT) {                                                       \
            const int t_ = (S);                                               \
            if ((t_ & 31) == 0) {                                             \
                X[lane] = xpre;                                               \
                __builtin_amdgcn_wave_barrier();                              \
                if (t_ + 32 < NT) { xpre = xg[lane]; xg += 64; }              \
            }                                                                 \
            const f2 x2_ = ((const f2*)X)[t_ & 31];                           \
            f2 hp_[8];                                                        \
            LOAD_H16(hp_, &H0[Q][0]);                                         \
            f2 a0_ = wh[0] * hp_[0]; a0_.x += bias;                           \
            f2 a1_ = wh[1] * hp_[1];                                          \
            f2 a2_ = wh[2] * hp_[2];                                          \
            f2 a3_ = wh[3] * hp_[3];                                          \
            a0_ = wh[4] * hp_[4] + a0_;                                       \
            a1_ = wh[5] * hp_[5] + a1_;                                       \
            a2_ = wh[6] * hp_[6] + a2_;                                       \
            a3_ = wh[7] * hp_[7] + a3_;                                       \
            a0_ = (a0_ + a1_) + (a2_ + a3_);                                  \
            float pre_ = a0_.x + a0_.y;                                       \
            pre_ = fmaf(wix.x, x2_.x, pre_);                                  \
            pre_ = fmaf(wix.y, x2_.y, pre_);                                  \
            float hn_;                                                        \
            GATE(pre_, c, hn_);                                               \
            H0[P][row] = hn_;                                                 \
        }                                                                     \
    } else if (w == 1) {                                                      \
        if ((S) >= 1 && (S) < NT + 1) {                                       \
            f2 hp_[8], hi_[8];                                                \
            LOAD_H16(hi_, &H0[Q][0]);                                         \
            LOAD_H16(hp_, &H1[P][0]);                                         \
            f2 a0_ = wh[0] * hp_[0]; a0_.x += bias;                           \
            f2 a1_ = wh[1] * hp_[1];                                          \
            f2 a2_ = wh[2] * hp_[2];                                          \
            f2 a3_ = wh[3] * hp_[3];                                          \
            a0_ = wh[4] * hp_[4] + a0_;                                       \
            a1_ = wh[5] * hp_[5] + a1_;                                       \
            a2_ = wh[6] * hp_[6] + a2_;                                       \
            a3_ = wh[7] * hp_[7] + a3_;                                       \
            a0_ = wi[0] * hi_[0] + a0_;                                       \
            a1_ = wi[1] * hi_[1] + a1_;                                       \
            a2_ = wi[2] * hi_[2] + a2_;                                       \
            a3_ = wi[3] * hi_[3] + a3_;                                       \
            a0_ = wi[4] * hi_[4] + a0_;                                       \
            a1_ = wi[5] * hi_[5] + a1_;                                       \
            a2_ = wi[6] * hi_[6] + a2_;                                       \
            a3_ = wi[7] * hi_[7] + a3_;                                       \
            a0_ = (a0_ + a1_) + (a2_ + a3_);                                  \
            float pre_ = a0_.x + a0_.y;                                       \
            float hn_;                                                        \
            GATE(pre_, c, hn_);                                               \
            H1[Q][row] = hn_;                                                 \
        }                                                                     \
    } else {                                                                  \
        if ((S) >= 2) {                                                       \
            f2 hp_[8], hi_[8];                                                \
            LOAD_H16(hi_, &H1[P][0]);                                         \
            LOAD_H16(hp_, &H2[Q][0]);                                         \
            f2 a0_ = wh[0] * hp_[0]; a0_.x += bias;                           \
            f2 a1_ = wh[1] * hp_[1];                                          \
            f2 a2_ = wh[2] * hp_[2];                                          \
            f2 a3_ = wh[3] * hp_[3];                                          \
            a0_ = wh[4] * hp_[4] + a0_;                                       \
            a1_ = wh[5] * hp_[5] + a1_;                                       \
            a2_ = wh[6] * hp_[6] + a2_;                                       \
            a3_ = wh[7] * hp_[7] + a3_;                                       \
            a0_ = wi[0] * hi_[0] + a0_;                                       \
            a1_ = wi[1] * hi_[1] + a1_;                                       \
            a2_ = wi[2] * hi_[2] + a2_;                                       \
            a3_ = wi[3] * hi_[3] + a3_;                                       \
            a0_ = wi[4] * hi_[4] + a0_;                                       \
            a1_ = wi[5] * hi_[5] + a1_;                                       \
            a2_ = wi[6] * hi_[6] + a2_;                                       \
            a3_ = wi[7] * hi_[7] + a3_;                                       \
            a0_ = (a0_ + a1_) + (a2_ + a3_);                                  \
            float pre_ = a0_.x + a0_.y;                                       \
            float hn_;                                                        \
            GATE(pre_, c, hn_);                                               \
            H2[P][row] = hn_;                                                 \
        }                                                                     \
    }                                                                         \
}

__global__ __launch_bounds__(192, 6) void lstm3_kernel(
    const float* __restrict__ x,
    const float* __restrict__ h0,
    const float* __restrict__ c0,
    const float* __restrict__ Wih0, const float* __restrict__ Whh0,
    const float* __restrict__ bih0, const float* __restrict__ bhh0,
    const float* __restrict__ Wih1, const float* __restrict__ Whh1,
    const float* __restrict__ bih1, const float* __restrict__ bhh1,
    const float* __restrict__ Wih2, const float* __restrict__ Whh2,
    const float* __restrict__ bih2, const float* __restrict__ bhh2,
    const float* __restrict__ Wfc,  const float* __restrict__ bfc,
    float* __restrict__ out)
{
    // Wide 64-slot buffers: lane 4q+g writes slot g*16+q; slots 0..15 == h[0..15].
    __shared__ float H0[2][64], H1[2][64], H2[2][64];
    __shared__ float X[64];    // wave0-private x staging: 32 steps * 2 floats

    const int lane = threadIdx.x & 63;
    const int w    = threadIdx.x >> 6;   // wave index == layer index
    const int b    = blockIdx.x;
    const int q    = lane >> 2;          // hidden unit 0..15
    const int g    = lane & 3;           // gate 0:i 1:f 2:g~ 3:o
    const int row  = g * 16 + q;         // PyTorch gate-row == LDS write slot

    const float kpre = (g == 2) ? -2.88539008177792681f : -1.44269504088896340f;
    const float kA   = (g == 2) ? 2.0f : 1.0f;
    const float kB   = (g == 2) ? -1.0f : 0.0f;

    // ---- select this wave's layer pointers (wave-uniform) ----
    const float* Wihp = (w == 0) ? Wih0 : (w == 1) ? Wih1 : Wih2;
    const float* Whhp = (w == 0) ? Whh0 : (w == 1) ? Whh1 : Whh2;
    const float* bihp = (w == 0) ? bih0 : (w == 1) ? bih1 : bih2;
    const float* bhhp = (w == 0) ? bhh0 : (w == 1) ? bhh1 : bhh2;

    // ---- per-lane weights for THIS layer only (<= 17 floats) ----
    f2 wh[8], wi[8];
    f2 wix;
#pragma unroll
    for (int k = 0; k < 4; ++k) {
        f4 t = *(const f4*)&Whhp[row * 16 + 4 * k];
        wh[2 * k]     = F2LO(t);
        wh[2 * k + 1] = F2HI(t);
    }
    if (w == 0) {
        wix = *(const f2*)&Wihp[row * 2];
    } else {
#pragma unroll
        for (int k = 0; k < 4; ++k) {
            f4 t = *(const f4*)&Wihp[row * 16 + 4 * k];
            wi[2 * k]     = F2LO(t);
            wi[2 * k + 1] = F2HI(t);
        }
    }
    const float bias = bihp[row] + bhhp[row];

    // ---- initial state: c per lane; h(-1) into parity-1 slot ----
    float c = c0[w * NB * 16 + b * 16 + q];
    float* Hown = (w == 0) ? &H0[0][0] : (w == 1) ? &H1[0][0] : &H2[0][0];
    if (lane < 16)
        Hown[64 + lane] = h0[w * NB * 16 + b * 16 + lane];

    // wave0 x prefetch
    const float* xg = x + (size_t)b * (NT * 2);
    float xpre = 0.0f;
    if (w == 0) { xpre = xg[lane]; xg += 64; }

    __syncthreads();

    int s = 0;
#pragma unroll 1
    for (int it = 0; it < (NT + 2) / 2; ++it) {
        STEP(s, 0, 1);
        ++s;
        __syncthreads();
        STEP(s, 1, 0);
        ++s;
        __syncthreads();
    }

    // ---- epilogue: out[b] = Wfc . h2(T-1) + bfc ; h2(1023) is in H2[1] ----
    if (w == 2) {
        f2 hp[8];
        LOAD_H16(hp, &H2[1][0]);
        f2 wf[8];
#pragma unroll
        for (int k = 0; k < 4; ++k) {
            f4 t = *(const f4*)&Wfc[4 * k];
            wf[2 * k]     = F2LO(t);
            wf[2 * k + 1] = F2HI(t);
        }
        f2 a0 = wf[0] * hp[0] + wf[1] * hp[1];
        f2 a1 = wf[2] * hp[2] + wf[3] * hp[3];
        a0 = wf[4] * hp[4] + a0;
        a1 = wf[5] * hp[5] + a1;
        a0 = wf[6] * hp[6] + a0;
        a1 = wf[7] * hp[7] + a1;
        a0 = a0 + a1;
        if (lane == 0)
            out[b] = a0.x + a0.y + bfc[0];
    }
}

extern "C" void kernel_launch(void* const* d_in, const int* in_sizes, int n_in,
                              void* d_out, int out_size, void* d_ws, size_t ws_size,
                              hipStream_t stream) {
    (void)in_sizes; (void)n_in; (void)d_ws; (void)ws_size; (void)out_size;
    const float* x    = (const float*)d_in[0];
    const float* h0   = (const float*)d_in[1];
    const float* c0   = (const float*)d_in[2];
    const float* Wih0 = (const float*)d_in[3];
    const float* Whh0 = (const float*)d_in[4];
    const float* bih0 = (const float*)d_in[5];
    const float* bhh0 = (const float*)d_in[6];
    const float* Wih1 = (const float*)d_in[7];
    const float* Whh1 = (const float*)d_in[8];
    const float* bih1 = (const float*)d_in[9];
    const float* bhh1 = (const float*)d_in[10];
    const float* Wih2 = (const float*)d_in[11];
    const float* Whh2 = (const float*)d_in[12];
    const float* bih2 = (const float*)d_in[13];
    const float* bhh2 = (const float*)d_in[14];
    const float* Wfc  = (const float*)d_in[15];
    const float* bfc  = (const float*)d_in[16];
    float* out = (float*)d_out;

    lstm3_kernel<<<NB, 192, 0, stream>>>(
        x, h0, c0, Wih0, Whh0, bih0, bhh0, Wih1, Whh1, bih1, bhh1,
        Wih2, Whh2, bih2, bhh2, Wfc, bfc, out);
}